// Round 3
// baseline (528.333 us; speedup 1.0000x reference)
//
#include <hip/hip_runtime.h>
#include <hip/hip_fp16.h>
#include <cstdint>
#include <cstddef>

#define N_NODES 100000
#define N_PAD 100096      // N rounded up to 128 (gemm row-tile)
#define N_EDGES 1600000
#define D 128
#define NLAYERS 3
#define NB 3125       // buckets of 32 nodes
#define NBLK_E 128    // edge-phase blocks
#define EPB 12500     // edges per block: 1600000/128
#define ENT_CAP 1024  // fill2 LDS entries; bucket max ~600 (22 sigma)

typedef float f2v __attribute__((ext_vector_type(2)));
typedef float f4v __attribute__((ext_vector_type(4)));

// ---------------- CSR build: LDS-histogram counting sort (no global atomics) ----------------

__global__ __launch_bounds__(512) void hist1_kernel(const int* __restrict__ col,
                                                    int* __restrict__ hmat) {
    __shared__ int hist[NB];
    int b = blockIdx.x, t = threadIdx.x;
    for (int j = t; j < NB; j += 512) hist[j] = 0;
    __syncthreads();
    int base = b * EPB;
    for (int i = t; i < EPB; i += 512) {
        int c = col[base + i];
        atomicAdd(&hist[c >> 5], 1);  // LDS atomic
    }
    __syncthreads();
    for (int j = t; j < NB; j += 512) hmat[b * NB + j] = hist[j];
}

__global__ void btot_kernel(const int* __restrict__ hmat, int* __restrict__ btot) {
    int j = blockIdx.x * 256 + threadIdx.x;
    if (j < NB) {
        int s = 0;
        for (int b = 0; b < NBLK_E; b++) s += hmat[b * NB + j];
        btot[j] = s;
    }
}

// Single-block exclusive scan over 3125 bucket totals -> bstart (+ sentinel).
__global__ void bscan_kernel(const int* __restrict__ btot, int* __restrict__ bstart, int nb, int e) {
    __shared__ int lsum[1024];
    int t = threadIdx.x;
    int vals[4];
    int v0 = 0;
#pragma unroll
    for (int j = 0; j < 4; j++) {
        int idx = t * 4 + j;
        int c = (idx < nb) ? btot[idx] : 0;
        vals[j] = c;
        v0 += c;
    }
    lsum[t] = v0;
    __syncthreads();
    for (int off = 1; off < 1024; off <<= 1) {
        int x = (t >= off) ? lsum[t - off] : 0;
        __syncthreads();
        lsum[t] += x;
        __syncthreads();
    }
    int base = lsum[t] - v0;  // exclusive
#pragma unroll
    for (int j = 0; j < 4; j++) {
        int idx = t * 4 + j;
        if (idx < nb) {
            bstart[idx] = base;
            base += vals[j];
        }
    }
    if (t == 0) bstart[nb] = e;
}

// Per-(block,bucket) start offsets: hoff[b][j] = bstart[j] + sum_{b'<b} hmat[b'][j]
__global__ void hoff_kernel(const int* __restrict__ hmat, const int* __restrict__ bstart,
                            int* __restrict__ hoff) {
    int j = blockIdx.x * 256 + threadIdx.x;
    if (j < NB) {
        int run = bstart[j];
        for (int b = 0; b < NBLK_E; b++) {
            hoff[b * NB + j] = run;
            run += hmat[b * NB + j];
        }
    }
}

// Scatter edges to exact bucket-sorted positions. LDS cursors, no global atomics.
__global__ __launch_bounds__(512) void scatter_kernel(const int* __restrict__ row,
                                                      const int* __restrict__ col,
                                                      const int* __restrict__ hoff,
                                                      unsigned* __restrict__ bucketbuf) {
    __shared__ int cur[NB];
    int b = blockIdx.x, t = threadIdx.x;
    for (int j = t; j < NB; j += 512) cur[j] = hoff[b * NB + j];
    __syncthreads();
    int base = b * EPB;
    for (int i = t; i < EPB; i += 512) {
        int r = row[base + i], c = col[base + i];
        int pos = atomicAdd(&cur[c >> 5], 1);  // LDS atomic
        bucketbuf[pos] = ((unsigned)r << 5) | (unsigned)(c & 31);
    }
}

// One block per bucket: LDS histogram of 32 local cols -> per-node offsets,
// dinv, and localized CSR scatter (contiguous ~2KB range, LDS cursors).
__global__ void fill2_kernel(const unsigned* __restrict__ bucketbuf, const int* __restrict__ bstart,
                             int* __restrict__ offsets, float* __restrict__ dinv,
                             int* __restrict__ src, int n, int e) {
    __shared__ unsigned ent[ENT_CAP];
    __shared__ int hist[32];
    __shared__ int cur[32];
    __shared__ int loff[32];
    int b = blockIdx.x, t = threadIdx.x;
    int s0 = bstart[b];
    int cnt = bstart[b + 1] - s0;
    if (cnt > ENT_CAP) cnt = ENT_CAP;
    if (t < 32) hist[t] = 0;
    __syncthreads();
    for (int i = t; i < cnt; i += 256) {
        unsigned v = bucketbuf[s0 + i];
        ent[i] = v;
        atomicAdd(&hist[v & 31], 1);
    }
    __syncthreads();
    if (t == 0) {
        int run = s0;
#pragma unroll
        for (int j = 0; j < 32; j++) {
            loff[j] = run;
            run += hist[j];
        }
    }
    __syncthreads();
    if (t < 32) {
        int node = b * 32 + t;
        int o = loff[t];
        offsets[node] = o;
        cur[t] = o;
        dinv[node] = rsqrtf((float)(hist[t] + 1));  // +1 self loop
    }
    if (b == 0 && t == 0) offsets[n] = e;
    __syncthreads();
    for (int i = t; i < cnt; i += 256) {
        unsigned v = ent[i];
        int pos = atomicAdd(&cur[v & 31], 1);
        src[pos] = (int)(v >> 5);
    }
}

// ---------------- per-layer kernels ----------------

// Cast + pre-scale: xs[v] = fp16(dinv[v] * emb[v]). Pre-scaling removes the
// per-edge dinv[src] gather + multiply from the agg inner loop.
__global__ void cast_kernel(const float2* __restrict__ in, const float* __restrict__ dinv,
                            __half2* __restrict__ out, int n2) {
    int i = blockIdx.x * 256 + threadIdx.x;
    if (i < n2) {
        float d = dinv[i >> 6];  // wave-uniform (64 half2 per node)
        float2 v = in[i];
        out[i] = __floats2half2_rn(d * v.x, d * v.y);
    }
}

// One 64-thread block (=1 wave) per node; each thread owns a half2 pair.
// xs is PRE-SCALED: xs[v] = dinv[v]*x[v]. So:
//   out[v] = dinv[v] * ( xs[v] + sum_e xs[src_e] ), fp32 accum.
// 8-wide unroll keeps 8 x 256B gathers in flight per wave; chain is just
// src -> gather -> add. Output (51.2MB fp32) stored nontemporal so the write
// stream doesn't evict xs rows (the gather working set) from L2.
__global__ void agg_kernel(const __half2* __restrict__ xs, const int* __restrict__ offs,
                           float* __restrict__ out, const float* __restrict__ dinv,
                           const int* __restrict__ src) {
    int v = blockIdx.x;
    int f = threadIdx.x;  // 0..63
    float dv = dinv[v];
    float2 a0 = __half22float2(xs[(size_t)v * 64 + f]);  // self term (already scaled)
    float ax = a0.x;
    float ay = a0.y;
    int i = offs[v], s1 = offs[v + 1];
    // full 8-groups
    for (; i + 7 < s1; i += 8) {
        int s[8];
#pragma unroll
        for (int j = 0; j < 8; j++) s[j] = src[i + j];
        float2 x[8];
#pragma unroll
        for (int j = 0; j < 8; j++) x[j] = __half22float2(xs[(size_t)s[j] * 64 + f]);
#pragma unroll
        for (int j = 0; j < 8; j++) {
            ax += x[j].x;
            ay += x[j].y;
        }
    }
    // masked tail group (clamped index re-gathers a cached row; contribution zeroed)
    if (i < s1) {
        int last = s1 - 1;
        int s[8];
        float m[8];
#pragma unroll
        for (int j = 0; j < 8; j++) {
            int idx = i + j;
            bool in = idx < s1;
            s[j] = src[in ? idx : last];
            m[j] = in ? 1.0f : 0.0f;
        }
        float2 x[8];
#pragma unroll
        for (int j = 0; j < 8; j++) x[j] = __half22float2(xs[(size_t)s[j] * 64 + f]);
#pragma unroll
        for (int j = 0; j < 8; j++) {
            ax += m[j] * x[j].x;
            ay += m[j] * x[j].y;
        }
    }
    f2v r;
    r.x = dv * ax;
    r.y = dv * ay;
    __builtin_nontemporal_store(r, (f2v*)out + (size_t)v * 64 + f);
}

// out[M x 128] = relu(A[M x 128] @ W[128 x 128] + bias).
// BM=128, 8x8 outputs/thread, K chunked by 32. vs prior round, two fixes from
// the 3.6M SQ_LDS_BANK_CONFLICT + latency-bound post-mortem:
//  (1) W-reads: cols split as {tx*4, 64+tx*4} -> 16B-stride lane addresses
//      (R1-verified conflict-free pattern) instead of 8-contiguous (32B
//      stride, 2-way conflict per 8-lane phase).
//  (2) Software pipeline: next K-chunk prefetched into registers during the
//      compute phase (T14 issue-early/write-late), so the ~900cy global
//      latency of the NT aggbuf stream hides under the 32-k FMA loop.
// A staged transposed [k][row^swz] so compute a-reads are 4-address
// broadcasts. All fp32.
__global__ __launch_bounds__(256) void gemm_bias_relu_kernel(
    const float* __restrict__ A, const float* __restrict__ W,
    const float* __restrict__ bias, float* __restrict__ out,
    __half2* __restrict__ xs_out, const float* __restrict__ dinv,
    int write_h, int write_out, int n) {
    __shared__ float sA[32 * 128];  // [k][row^swz] fp32, 16 KB
    __shared__ float sW[32 * 128];  // [k][col] fp32, 16 KB
    int t = threadIdx.x;
    int tx = t & 15;   // col-group: cols {tx*4..tx*4+3} and {64+tx*4..+3}
    int ty = t >> 4;   // row-group: rows ty*8 .. ty*8+7
    int row0 = blockIdx.x * 128;

    f4v acc[8][2];
#pragma unroll
    for (int r = 0; r < 8; r++) {
        acc[r][0] = (f4v){0.f, 0.f, 0.f, 0.f};
        acc[r][1] = (f4v){0.f, 0.f, 0.f, 0.f};
    }

    const f4v* A4 = (const f4v*)A;
    const f4v* W4 = (const f4v*)W;

    // prefetch registers: one K-chunk of A (transposed on LDS-write) + W
    f4v av[4], wv[4];

#define LOADCH(kc)                                                                   \
    {                                                                                \
        _Pragma("unroll") for (int i = 0; i < 4; i++) {                              \
            int idx = t + 256 * i;                                                   \
            int rr = idx >> 3, qq = idx & 7;                                         \
            av[i] = __builtin_nontemporal_load(                                      \
                &A4[(size_t)(row0 + rr) * 32 + (kc) * 8 + qq]);                      \
            wv[i] = W4[(size_t)(kc) * 1024 + idx];                                   \
        }                                                                            \
    }

#define STORECH()                                                                    \
    {                                                                                \
        f4v* sW4 = (f4v*)sW;                                                         \
        _Pragma("unroll") for (int i = 0; i < 4; i++) {                              \
            int idx = t + 256 * i;                                                   \
            int rr = idx >> 3, qq = idx & 7;                                         \
            int k0 = qq * 4;                                                         \
            f4v v = av[i];                                                           \
            sA[(k0 + 0) * 128 + (rr ^ ((k0 + 0) & 24))] = v.x;                       \
            sA[(k0 + 1) * 128 + (rr ^ ((k0 + 1) & 24))] = v.y;                       \
            sA[(k0 + 2) * 128 + (rr ^ ((k0 + 2) & 24))] = v.z;                       \
            sA[(k0 + 3) * 128 + (rr ^ ((k0 + 3) & 24))] = v.w;                       \
            sW4[idx] = wv[i];                                                        \
        }                                                                            \
    }

    LOADCH(0);
#pragma unroll
    for (int kc = 0; kc < 4; kc++) {
        __syncthreads();  // previous chunk's compute done; safe to overwrite LDS
        STORECH();        // vmcnt wait for this chunk's loads (hidden under prev compute)
        if (kc < 3) LOADCH(kc + 1);  // issue next loads; fly during this compute
        __syncthreads();  // staging visible

#pragma unroll 8
        for (int k = 0; k < 32; k++) {
            const float* ap = &sA[k * 128 + ((ty * 8) ^ (k & 24))];
            f4v a0 = *(const f4v*)ap;
            f4v a1 = *(const f4v*)(ap + 4);
            f4v b0 = *(const f4v*)&sW[k * 128 + tx * 4];        // 16B-stride: conflict-free
            f4v b1 = *(const f4v*)&sW[k * 128 + 64 + tx * 4];
#pragma unroll
            for (int r = 0; r < 4; r++) {
                acc[r][0] += a0[r] * b0;
                acc[r][1] += a0[r] * b1;
                acc[r + 4][0] += a1[r] * b0;
                acc[r + 4][1] += a1[r] * b1;
            }
        }
    }
#undef LOADCH
#undef STORECH

    // ---- epilogue: bias + relu, guarded stores (last block is partial) ----
    f4v bb0 = ((const f4v*)bias)[tx];
    f4v bb1 = ((const f4v*)bias)[16 + tx];
#pragma unroll
    for (int r = 0; r < 8; r++) {
        int rowi = row0 + ty * 8 + r;
        if (rowi >= n) continue;
        f4v o0 = acc[r][0] + bb0;
        f4v o1 = acc[r][1] + bb1;
#pragma unroll
        for (int j = 0; j < 4; j++) {
            o0[j] = fmaxf(o0[j], 0.0f);
            o1[j] = fmaxf(o1[j], 0.0f);
        }
        if (write_out) {
            __builtin_nontemporal_store(o0, (f4v*)out + (size_t)rowi * 32 + tx);
            __builtin_nontemporal_store(o1, (f4v*)out + (size_t)rowi * 32 + 16 + tx);
        }
        if (write_h) {
            float dr = dinv[rowi];
            __half2 h0[2], h1[2];
            h0[0] = __floats2half2_rn(dr * o0[0], dr * o0[1]);
            h0[1] = __floats2half2_rn(dr * o0[2], dr * o0[3]);
            h1[0] = __floats2half2_rn(dr * o1[0], dr * o1[1]);
            h1[1] = __floats2half2_rn(dr * o1[2], dr * o1[3]);
            *(uint2*)&xs_out[(size_t)rowi * 64 + tx * 2] = *(uint2*)h0;
            *(uint2*)&xs_out[(size_t)rowi * 64 + 32 + tx * 2] = *(uint2*)h1;
        }
    }
}

// ---------------- launch ----------------

extern "C" void kernel_launch(void* const* d_in, const int* in_sizes, int n_in,
                              void* d_out, int out_size, void* d_ws, size_t ws_size,
                              hipStream_t stream) {
    const int* edge = (const int*)d_in[0];   // [2, E] int32
    const float* emb = (const float*)d_in[1];
    const float* Ws = (const float*)d_in[2]; // [L, D, D]
    const float* bs = (const float*)d_in[3]; // [L, D]
    float* out = (float*)d_out;

    const int n = N_NODES, e = N_EDGES;
    const int* row = edge;       // sources
    const int* col = edge + e;   // targets

    char* p = (char*)d_ws;
    float* aggbuf = (float*)p;
    int* hmat = (int*)p;                      // aliases aggbuf (dead until first agg)
    int* hoff = hmat + (size_t)NBLK_E * NB;
    p += (size_t)N_PAD * D * 4;               // 51.25 MB (padded to 128-row tiles)
    __half2* xs = (__half2*)p;                // 25.6 MB (pre-scaled fp16 features)
    unsigned* bucketbuf = (unsigned*)p;       // aliases xs: dead before cast runs
    p += (size_t)n * D * 2;
    int* csr_src  = (int*)p;    p += (size_t)e * 4;           // 6.4 MB
    float* dinv   = (float*)p;  p += (size_t)n * 4;
    int* offsets  = (int*)p;    p += (size_t)(n + 1) * 4;
    int* btot     = (int*)p;    p += (size_t)NB * 4;
    int* bstart   = (int*)p;    p += (size_t)(NB + 1) * 4;

    hist1_kernel<<<NBLK_E, 512, 0, stream>>>(col, hmat);
    btot_kernel<<<(NB + 255) / 256, 256, 0, stream>>>(hmat, btot);
    bscan_kernel<<<1, 1024, 0, stream>>>(btot, bstart, NB, e);
    hoff_kernel<<<(NB + 255) / 256, 256, 0, stream>>>(hmat, bstart, hoff);
    scatter_kernel<<<NBLK_E, 512, 0, stream>>>(row, col, hoff, bucketbuf);
    fill2_kernel<<<NB, 256, 0, stream>>>(bucketbuf, bstart, offsets, dinv, csr_src, n, e);

    int n2 = n * 64;  // half2 count
    cast_kernel<<<(n2 + 255) / 256, 256, 0, stream>>>((const float2*)emb, dinv, xs, n2);

    const int ngb = N_PAD / 128;  // 782 row-tiles
    for (int l = 0; l < NLAYERS; l++) {
        agg_kernel<<<n, 64, 0, stream>>>(xs, offsets, aggbuf, dinv, csr_src);
        gemm_bias_relu_kernel<<<ngb, 256, 0, stream>>>(
            aggbuf, Ws + (size_t)l * D * D, bs + (size_t)l * D, out,
            xs, dinv,
            (l < NLAYERS - 1) ? 1 : 0, (l == NLAYERS - 1) ? 1 : 0, n);
    }
}

// Round 5
// 493.661 us; speedup vs baseline: 1.0702x; 1.0702x over previous
//
#include <hip/hip_runtime.h>
#include <hip/hip_fp16.h>
#include <cstdint>
#include <cstddef>

#define N_NODES 100000
#define N_PAD 100096      // N rounded up to 128 (gemm row-tile)
#define N_EDGES 1600000
#define D 128
#define NLAYERS 3
#define NB 3125       // buckets of 32 nodes
#define NBLK_E 128    // edge-phase blocks
#define EPB 12500     // edges per block: 1600000/128
#define ENT_CAP 1024  // fill2 LDS entries; bucket max ~600 (22 sigma)

typedef float f2v __attribute__((ext_vector_type(2)));
typedef float f4v __attribute__((ext_vector_type(4)));
typedef _Float16 f16x8 __attribute__((ext_vector_type(8)));
typedef float f32x4 __attribute__((ext_vector_type(4)));
typedef unsigned u32x4 __attribute__((ext_vector_type(4)));

// ---------------- CSR build: LDS-histogram counting sort (no global atomics) ----------------

__global__ __launch_bounds__(512) void hist1_kernel(const int* __restrict__ col,
                                                    int* __restrict__ hmat) {
    __shared__ int hist[NB];
    int b = blockIdx.x, t = threadIdx.x;
    for (int j = t; j < NB; j += 512) hist[j] = 0;
    __syncthreads();
    int base = b * EPB;
    for (int i = t; i < EPB; i += 512) {
        int c = col[base + i];
        atomicAdd(&hist[c >> 5], 1);  // LDS atomic
    }
    __syncthreads();
    for (int j = t; j < NB; j += 512) hmat[b * NB + j] = hist[j];
}

__global__ void btot_kernel(const int* __restrict__ hmat, int* __restrict__ btot) {
    int j = blockIdx.x * 256 + threadIdx.x;
    if (j < NB) {
        int s = 0;
        for (int b = 0; b < NBLK_E; b++) s += hmat[b * NB + j];
        btot[j] = s;
    }
}

// Single-block exclusive scan over 3125 bucket totals -> bstart (+ sentinel).
__global__ void bscan_kernel(const int* __restrict__ btot, int* __restrict__ bstart, int nb, int e) {
    __shared__ int lsum[1024];
    int t = threadIdx.x;
    int vals[4];
    int v0 = 0;
#pragma unroll
    for (int j = 0; j < 4; j++) {
        int idx = t * 4 + j;
        int c = (idx < nb) ? btot[idx] : 0;
        vals[j] = c;
        v0 += c;
    }
    lsum[t] = v0;
    __syncthreads();
    for (int off = 1; off < 1024; off <<= 1) {
        int x = (t >= off) ? lsum[t - off] : 0;
        __syncthreads();
        lsum[t] += x;
        __syncthreads();
    }
    int base = lsum[t] - v0;  // exclusive
#pragma unroll
    for (int j = 0; j < 4; j++) {
        int idx = t * 4 + j;
        if (idx < nb) {
            bstart[idx] = base;
            base += vals[j];
        }
    }
    if (t == 0) bstart[nb] = e;
}

// Per-(block,bucket) start offsets: hoff[b][j] = bstart[j] + sum_{b'<b} hmat[b'][j]
__global__ void hoff_kernel(const int* __restrict__ hmat, const int* __restrict__ bstart,
                            int* __restrict__ hoff) {
    int j = blockIdx.x * 256 + threadIdx.x;
    if (j < NB) {
        int run = bstart[j];
        for (int b = 0; b < NBLK_E; b++) {
            hoff[b * NB + j] = run;
            run += hmat[b * NB + j];
        }
    }
}

// Scatter edges to exact bucket-sorted positions. LDS cursors, no global atomics.
__global__ __launch_bounds__(512) void scatter_kernel(const int* __restrict__ row,
                                                      const int* __restrict__ col,
                                                      const int* __restrict__ hoff,
                                                      unsigned* __restrict__ bucketbuf) {
    __shared__ int cur[NB];
    int b = blockIdx.x, t = threadIdx.x;
    for (int j = t; j < NB; j += 512) cur[j] = hoff[b * NB + j];
    __syncthreads();
    int base = b * EPB;
    for (int i = t; i < EPB; i += 512) {
        int r = row[base + i], c = col[base + i];
        int pos = atomicAdd(&cur[c >> 5], 1);  // LDS atomic
        bucketbuf[pos] = ((unsigned)r << 5) | (unsigned)(c & 31);
    }
}

// One block per bucket: LDS histogram of 32 local cols -> per-node offsets,
// dinv, and localized CSR scatter (contiguous ~2KB range, LDS cursors).
__global__ void fill2_kernel(const unsigned* __restrict__ bucketbuf, const int* __restrict__ bstart,
                             int* __restrict__ offsets, float* __restrict__ dinv,
                             int* __restrict__ src, int n, int e) {
    __shared__ unsigned ent[ENT_CAP];
    __shared__ int hist[32];
    __shared__ int cur[32];
    __shared__ int loff[32];
    int b = blockIdx.x, t = threadIdx.x;
    int s0 = bstart[b];
    int cnt = bstart[b + 1] - s0;
    if (cnt > ENT_CAP) cnt = ENT_CAP;
    if (t < 32) hist[t] = 0;
    __syncthreads();
    for (int i = t; i < cnt; i += 256) {
        unsigned v = bucketbuf[s0 + i];
        ent[i] = v;
        atomicAdd(&hist[v & 31], 1);
    }
    __syncthreads();
    if (t == 0) {
        int run = s0;
#pragma unroll
        for (int j = 0; j < 32; j++) {
            loff[j] = run;
            run += hist[j];
        }
    }
    __syncthreads();
    if (t < 32) {
        int node = b * 32 + t;
        int o = loff[t];
        offsets[node] = o;
        cur[t] = o;
        dinv[node] = rsqrtf((float)(hist[t] + 1));  // +1 self loop
    }
    if (b == 0 && t == 0) offsets[n] = e;
    __syncthreads();
    for (int i = t; i < cnt; i += 256) {
        unsigned v = ent[i];
        int pos = atomicAdd(&cur[v & 31], 1);
        src[pos] = (int)(v >> 5);
    }
}

// ---------------- per-layer kernels ----------------

// Cast + pre-scale: xs[v] = fp16(dinv[v] * emb[v]). Pre-scaling removes the
// per-edge dinv[src] gather + multiply from the agg inner loop.
__global__ void cast_kernel(const float2* __restrict__ in, const float* __restrict__ dinv,
                            __half2* __restrict__ out, int n2) {
    int i = blockIdx.x * 256 + threadIdx.x;
    if (i < n2) {
        float d = dinv[i >> 6];  // wave-uniform (64 half2 per node)
        float2 v = in[i];
        out[i] = __floats2half2_rn(d * v.x, d * v.y);
    }
}

// W pre-split for the hi/lo fp16 MFMA: WhT/WlT[l][col][k] (transposed,
// fragment-ready). w = wh + wl with wh=fp16(w), wl=fp16(w-wh): 22-bit
// combined mantissa -> GEMM error ~2^-20, far below the fp16-gather noise.
__global__ void wsplit_kernel(const float* __restrict__ W,
                              _Float16* __restrict__ Wh, _Float16* __restrict__ Wl) {
    int c = blockIdx.x, l = blockIdx.y, k = threadIdx.x;  // 128 threads
    float w = W[(size_t)l * 16384 + k * 128 + c];
    _Float16 h = (_Float16)w;
    float r = w - (float)h;
    Wh[(size_t)l * 16384 + c * 128 + k] = h;
    Wl[(size_t)l * 16384 + c * 128 + k] = (_Float16)r;
}

// One 64-thread block (=1 wave) per node; each thread owns a half2 pair.
// xs is PRE-SCALED: xs[v] = dinv[v]*x[v]. So:
//   a[v] = dinv[v] * ( xs[v] + sum_e xs[src_e] ), fp32 accum.
// Output written as hi/lo fp16 PLANES (Ah, Al) feeding the MFMA gemm:
// a = ah + al captures ~22 mantissa bits. Same bytes as the old fp32
// write (4 B/elem), NT-stored so the stream doesn't evict xs from L2.
__global__ void agg_kernel(const __half2* __restrict__ xs, const int* __restrict__ offs,
                           unsigned* __restrict__ Ah, unsigned* __restrict__ Al,
                           const float* __restrict__ dinv, const int* __restrict__ src) {
    int v = blockIdx.x;
    int f = threadIdx.x;  // 0..63
    float dv = dinv[v];
    float2 a0 = __half22float2(xs[(size_t)v * 64 + f]);  // self term (already scaled)
    float ax = a0.x;
    float ay = a0.y;
    int i = offs[v], s1 = offs[v + 1];
    // full 8-groups
    for (; i + 7 < s1; i += 8) {
        int s[8];
#pragma unroll
        for (int j = 0; j < 8; j++) s[j] = src[i + j];
        float2 x[8];
#pragma unroll
        for (int j = 0; j < 8; j++) x[j] = __half22float2(xs[(size_t)s[j] * 64 + f]);
#pragma unroll
        for (int j = 0; j < 8; j++) {
            ax += x[j].x;
            ay += x[j].y;
        }
    }
    // masked tail group (clamped index re-gathers a cached row; contribution zeroed)
    if (i < s1) {
        int last = s1 - 1;
        int s[8];
        float m[8];
#pragma unroll
        for (int j = 0; j < 8; j++) {
            int idx = i + j;
            bool in = idx < s1;
            s[j] = src[in ? idx : last];
            m[j] = in ? 1.0f : 0.0f;
        }
        float2 x[8];
#pragma unroll
        for (int j = 0; j < 8; j++) x[j] = __half22float2(xs[(size_t)s[j] * 64 + f]);
#pragma unroll
        for (int j = 0; j < 8; j++) {
            ax += m[j] * x[j].x;
            ay += m[j] * x[j].y;
        }
    }
    float rx = dv * ax, ry = dv * ay;
    __half2 h2 = __floats2half2_rn(rx, ry);
    float2 hb = __half22float2(h2);
    __half2 l2 = __floats2half2_rn(rx - hb.x, ry - hb.y);
    __builtin_nontemporal_store(__builtin_bit_cast(unsigned, h2), Ah + (size_t)v * 64 + f);
    __builtin_nontemporal_store(__builtin_bit_cast(unsigned, l2), Al + (size_t)v * 64 + f);
}

// out[M x 128] = relu(A[M x 128] @ W[128 x 128] + bias) via MFMA.
// Rationale (R3 post-mortem): the fp32 VALU gemm is stuck at 63us — only one
// 4-wave block resident per CU (782 blocks ~ 3 lockstep rounds of 1/CU), so
// ds_read->FMA latency is exposed; and even at full occupancy the fp32 path
// has a 1.5x-oversubscribed-LDS floor (~31us). MFMA moves the 3.28 GFLOP to
// the matrix pipe (~1.3us) and makes the kernel memory-streaming-bound
// (~13us floor). Precision via hi/lo fp16 split, 3 terms:
//   a.w ~= ah.wh + al.wh + ah.wl   (al.bl term ~2^-22, dropped)
// MFMA 16x16x32_f16 fragment mapping (learn_hip m89-verified family):
//   A: row=lane&15, k-block by lane>>4;  B: col=lane&15, same k-map;
//   C/D: col=lane&15, row=(lane>>4)*4+reg.
// Any within-frag k-permutation applied identically to A and B cancels, so
// LDS tiles are stored [row/col][kgroup][8 f16] with an 80-B row pitch
// (16-B frag reads at 80-B stride -> <=2-way bank aliasing, free per m136).
__global__ __launch_bounds__(256) void gemm_mfma_kernel(
    const _Float16* __restrict__ Ahp, const _Float16* __restrict__ Alp,
    const _Float16* __restrict__ Whp, const _Float16* __restrict__ Wlp,  // [col][k]
    const float* __restrict__ bias, float* __restrict__ out,
    __half2* __restrict__ xs_out, const float* __restrict__ dinv,
    int write_h, int write_out, int nrows) {
    __shared__ _Float16 sA[2][128][40];  // [plane][row][4 kg * 8 + 8 pad] = 20 KB
    __shared__ _Float16 sW[2][128][40];  // [plane][col][...]              = 20 KB
    int t = threadIdx.x;
    int lane = t & 63, wv = t >> 6;
    int lrow = lane & 15, kg = lane >> 4;
    int row0 = blockIdx.x * 128;

    f32x4 acc[2][8];
#pragma unroll
    for (int m = 0; m < 2; m++)
#pragma unroll
        for (int nn = 0; nn < 8; nn++) acc[m][nn] = (f32x4){0.f, 0.f, 0.f, 0.f};

    const u32x4* Aq[2] = {(const u32x4*)Ahp, (const u32x4*)Alp};
    const u32x4* Wq[2] = {(const u32x4*)Whp, (const u32x4*)Wlp};

    u32x4 av[4], wvr[4];

    // slot decode: sid = t + 256*i; plane p = i>>1; rr = (sid>>2)&127 (row/col);
    // k2 = sid&3 (16-B k-group). Global row stride = 16 u32x4 (128 f16).
#define LOADCH(kc)                                                                    \
    {                                                                                 \
        _Pragma("unroll") for (int i = 0; i < 4; i++) {                               \
            int sid = t + 256 * i;                                                    \
            int p = i >> 1;                                                           \
            int rr = (sid >> 2) & 127;                                                \
            int k2 = sid & 3;                                                         \
            av[i] = __builtin_nontemporal_load(                                       \
                &Aq[p][(size_t)(row0 + rr) * 16 + (kc) * 4 + k2]);                    \
            wvr[i] = Wq[p][(size_t)rr * 16 + (kc) * 4 + k2];                          \
        }                                                                             \
    }

#define STORECH()                                                                     \
    {                                                                                 \
        _Pragma("unroll") for (int i = 0; i < 4; i++) {                               \
            int sid = t + 256 * i;                                                    \
            int p = i >> 1;                                                           \
            int rr = (sid >> 2) & 127;                                                \
            int k2 = sid & 3;                                                         \
            *(u32x4*)&sA[p][rr][k2 * 8] = av[i];                                      \
            *(u32x4*)&sW[p][rr][k2 * 8] = wvr[i];                                     \
        }                                                                             \
    }

    LOADCH(0);
#pragma unroll
    for (int kc = 0; kc < 4; kc++) {
        __syncthreads();                 // previous chunk's compute done
        STORECH();                       // waits this chunk's loads (hidden under prev MFMA)
        if (kc < 3) LOADCH(kc + 1);      // next chunk's loads fly during this compute
        __syncthreads();                 // staging visible

        // per wave: rows wv*32 .. wv*32+31 (2 M-frags), all 128 cols (8 N-frags)
        f16x8 a0h = *(const f16x8*)&sA[0][wv * 32 + lrow][kg * 8];
        f16x8 a1h = *(const f16x8*)&sA[0][wv * 32 + 16 + lrow][kg * 8];
        f16x8 a0l = *(const f16x8*)&sA[1][wv * 32 + lrow][kg * 8];
        f16x8 a1l = *(const f16x8*)&sA[1][wv * 32 + 16 + lrow][kg * 8];
#pragma unroll
        for (int nn = 0; nn < 8; nn++) {
            f16x8 bh = *(const f16x8*)&sW[0][nn * 16 + lrow][kg * 8];
            f16x8 bl = *(const f16x8*)&sW[1][nn * 16 + lrow][kg * 8];
            acc[0][nn] = __builtin_amdgcn_mfma_f32_16x16x32_f16(a0h, bh, acc[0][nn], 0, 0, 0);
            acc[0][nn] = __builtin_amdgcn_mfma_f32_16x16x32_f16(a0l, bh, acc[0][nn], 0, 0, 0);
            acc[0][nn] = __builtin_amdgcn_mfma_f32_16x16x32_f16(a0h, bl, acc[0][nn], 0, 0, 0);
            acc[1][nn] = __builtin_amdgcn_mfma_f32_16x16x32_f16(a1h, bh, acc[1][nn], 0, 0, 0);
            acc[1][nn] = __builtin_amdgcn_mfma_f32_16x16x32_f16(a1l, bh, acc[1][nn], 0, 0, 0);
            acc[1][nn] = __builtin_amdgcn_mfma_f32_16x16x32_f16(a1h, bl, acc[1][nn], 0, 0, 0);
        }
    }
#undef LOADCH
#undef STORECH

    // ---- epilogue: bias + relu; C/D frag: col=lane&15, row=(lane>>4)*4+reg ----
    float bcolv[8];
#pragma unroll
    for (int nn = 0; nn < 8; nn++) bcolv[nn] = bias[nn * 16 + lrow];
#pragma unroll
    for (int m = 0; m < 2; m++) {
        int rbase = row0 + wv * 32 + m * 16 + kg * 4;
#pragma unroll
        for (int j = 0; j < 4; j++) {
            int rowi = rbase + j;
            bool ok = rowi < nrows;
            float dvr = (ok && write_h) ? dinv[rowi] : 0.f;
#pragma unroll
            for (int nn = 0; nn < 8; nn++) {
                float o = fmaxf(acc[m][nn][j] + bcolv[nn], 0.f);
                float o2 = __shfl_xor(o, 1);  // partner col (lane^1): same rows, col+-1
                int col = nn * 16 + lrow;
                if (ok) {
                    if (write_out)
                        __builtin_nontemporal_store(o, out + (size_t)rowi * 128 + col);
                    if (write_h && !(lane & 1))
                        xs_out[(size_t)rowi * 64 + (col >> 1)] =
                            __floats2half2_rn(dvr * o, dvr * o2);
                }
            }
        }
    }
}

// ---------------- launch ----------------

extern "C" void kernel_launch(void* const* d_in, const int* in_sizes, int n_in,
                              void* d_out, int out_size, void* d_ws, size_t ws_size,
                              hipStream_t stream) {
    const int* edge = (const int*)d_in[0];   // [2, E] int32
    const float* emb = (const float*)d_in[1];
    const float* Ws = (const float*)d_in[2]; // [L, D, D]
    const float* bs = (const float*)d_in[3]; // [L, D]
    float* out = (float*)d_out;

    const int n = N_NODES, e = N_EDGES;
    const int* row = edge;       // sources
    const int* col = edge + e;   // targets

    char* p = (char*)d_ws;
    _Float16* Ah = (_Float16*)p;
    int* hmat = (int*)p;                      // aliases Ah (dead until first agg)
    int* hoff = hmat + (size_t)NBLK_E * NB;
    p += (size_t)N_PAD * D * 2;               // 25.62 MB  (hi plane)
    _Float16* Al = (_Float16*)p;
    p += (size_t)N_PAD * D * 2;               // 25.62 MB  (lo plane)
    __half2* xs = (__half2*)p;                // 25.6 MB (pre-scaled fp16 features)
    unsigned* bucketbuf = (unsigned*)p;       // aliases xs: dead before cast runs
    p += (size_t)n * D * 2;
    int* csr_src  = (int*)p;    p += (size_t)e * 4;           // 6.4 MB
    float* dinv   = (float*)p;  p += (size_t)n * 4;
    int* offsets  = (int*)p;    p += (size_t)(n + 1) * 4;
    int* btot     = (int*)p;    p += (size_t)NB * 4;
    int* bstart   = (int*)p;    p += (size_t)(NB + 1) * 4;
    _Float16* WhT = (_Float16*)p; p += (size_t)NLAYERS * D * D * 2;  // 98 KB
    _Float16* WlT = (_Float16*)p; p += (size_t)NLAYERS * D * D * 2;  // 98 KB

    hist1_kernel<<<NBLK_E, 512, 0, stream>>>(col, hmat);
    btot_kernel<<<(NB + 255) / 256, 256, 0, stream>>>(hmat, btot);
    bscan_kernel<<<1, 1024, 0, stream>>>(btot, bstart, NB, e);
    hoff_kernel<<<(NB + 255) / 256, 256, 0, stream>>>(hmat, bstart, hoff);
    scatter_kernel<<<NBLK_E, 512, 0, stream>>>(row, col, hoff, bucketbuf);
    fill2_kernel<<<NB, 256, 0, stream>>>(bucketbuf, bstart, offsets, dinv, csr_src, n, e);
    wsplit_kernel<<<dim3(128, NLAYERS), 128, 0, stream>>>(Ws, WhT, WlT);

    int n2 = n * 64;  // half2 count
    cast_kernel<<<(n2 + 255) / 256, 256, 0, stream>>>((const float2*)emb, dinv, xs, n2);

    const int ngb = N_PAD / 128;  // 782 row-tiles
    for (int l = 0; l < NLAYERS; l++) {
        agg_kernel<<<n, 64, 0, stream>>>(xs, offsets, (unsigned*)Ah, (unsigned*)Al,
                                         dinv, csr_src);
        gemm_mfma_kernel<<<ngb, 256, 0, stream>>>(
            Ah, Al, WhT + (size_t)l * D * D, WlT + (size_t)l * D * D,
            bs + (size_t)l * D, out, xs, dinv,
            (l < NLAYERS - 1) ? 1 : 0, (l == NLAYERS - 1) ? 1 : 0, n);
    }
}